// Round 12
// baseline (200.403 us; speedup 1.0000x reference)
//
#include <hip/hip_runtime.h>
#include <hip/hip_bf16.h>
#include <math.h>
#include <stdint.h>

typedef __attribute__((ext_vector_type(8))) short bf16x8;
typedef __attribute__((ext_vector_type(4))) float f32x4;

__device__ __forceinline__ uint32_t pack2(float a, float b) {
    union { __hip_bfloat162 h2; uint32_t u; } c;
    c.h2 = __float22bfloat162_rn(make_float2(a, b));   // v_cvt_pk_bf16_f32
    return c.u;
}
__device__ __forceinline__ unsigned short f2bf(float f) {
    union { __hip_bfloat16 h; unsigned short u; } c;
    c.h = __float2bfloat16(f);
    return c.u;
}
__device__ __forceinline__ float bf2f(unsigned short h) {
    union { uint32_t u; float f; } c; c.u = ((uint32_t)h) << 16;
    return c.f;
}
__device__ __forceinline__ float silu_f(float x) {
    return x / (1.0f + __expf(-x));
}

// Uniform cardinal cubic B-spline bases on grid g_i = -2.2 + 0.4*i.
// Identical to the reference Cox-de-Boor recursion on this uniform grid.
__device__ __forceinline__ void bspline8(float x, float* __restrict__ b) {
    const float tt = (x + 2.2f) * 2.5f;
#pragma unroll
    for (int v = 0; v < 8; ++v) {
        float y = fabsf(tt - (float)(v + 2));
        float p = fmaxf(2.0f - y, 0.0f);
        float q = fmaxf(1.0f - y, 0.0f);
        b[v] = (p * p * p - 4.0f * q * q * q) * (1.0f / 6.0f);
    }
}

// ---------------------------------------------------------------------------
// prep kernels
// ---------------------------------------------------------------------------
__global__ __launch_bounds__(256) void prep_ftw(const float* __restrict__ ftw,
                                                unsigned short* __restrict__ Wb) {
    const int idx = blockIdx.x * 256 + threadIdx.x;   // 98304 = 128*768
    Wb[idx] = f2bf(ftw[idx]);
}

__global__ __launch_bounds__(256) void prep_bp(const float* __restrict__ bw,
                                               const float* __restrict__ sw,
                                               unsigned short* __restrict__ Bp) {
    const int idx = blockIdx.x * 256 + threadIdx.x;   // 524288 = 128*4096
    const int n = idx >> 12;
    const int k = idx & 4095;
    const int f = k >> 4;
    const int v = k & 15;
    float val = 0.f;
    if (v == 0) val = bw[n * 256 + f];
    else if (v <= 8) val = sw[(size_t)(n * 256 + f) * 8 + (v - 1)];
    Bp[idx] = f2bf(val);
}

// ---------------------------------------------------------------------------
// FUSED, BM=64, 2 blocks/CU (LDS 64 KB).  B matrices (Wb 192 KB, Bp 1 MB)
// are L2-resident and read DIRECTLY into MFMA fragment registers -- no LDS
// staging for B, hence NO vmcnt drains anywhere in the main loops.
//   Phase 1: FT GEMM both sides (12 BK=128 tiles); A depth-2 named-reg
//            prefetch -> cvt -> swizzled smA; H -> smHT (transposed,
//            [256 feat][64 rows] bf16, chunk-swizzled), LDS only.
//   Phase 2: KAN1 expanded-A GEMM, 32 jb-steps, phi DOUBLE-buffered
//            (expand next while MFMA current); only lgkm waits at barriers.
//   Phase 3: KAN2 reduce + sigmoid.
// grid 512, block 512 (8 waves as 2x4; wave tile 32r x 32c).
// ---------------------------------------------------------------------------
__global__ __launch_bounds__(512, 4) void kan_fused(
        const float* __restrict__ stm, const float* __restrict__ nstm,
        const unsigned short* __restrict__ Wb, const float* __restrict__ bias,
        const unsigned short* __restrict__ Bp,
        const float* __restrict__ w2b, const float* __restrict__ w2s,
        float* __restrict__ out) {
    __shared__ alignas(16) char lds[65536];
    char* smA  = lds;            // 16 KB: ph1 A tile / ph2 phi0 / ph3 smH2
    char* phi1 = lds + 16384;    // 16 KB: ph2 phi1
    char* smHT = lds + 32768;    // 32 KB: H^T [256 feat][64 rows], swizzled

    const int r0 = blockIdx.x * 64;
    const int t = threadIdx.x;
    const int l = t & 63, w = t >> 6;
    const int fr = l & 15, h = l >> 4;
    const int wr = w >> 2, wc = w & 3;        // 2x4 wave grid, tile 32r x 32c

    // A staging geometry: thread -> row (t>>3), 16 floats at col (t&7)*16
    const int arow = t >> 3;
    const int acol = (t & 7) * 16;
    const uint32_t adst0 = (uint32_t)arow * 256u +
        ((uint32_t)(((t & 7) * 2) ^ (arow & 15)) << 4);
    const uint32_t adst1 = (uint32_t)arow * 256u +
        ((uint32_t)(((t & 7) * 2 + 1) ^ (arow & 15)) << 4);

    f32x4 acc[2][2];
#pragma unroll
    for (int mt = 0; mt < 2; ++mt)
#pragma unroll
        for (int nt = 0; nt < 2; ++nt) acc[mt][nt] = (f32x4){0.f, 0.f, 0.f, 0.f};

    float4 regY[4], regZ[4];
    bf16x8 bf[2][4];   // B fragments (always statically indexed)

#define FT_ISSUE(REG, TK)                                                      \
    {                                                                          \
        const float* __restrict__ Ap = ((TK) >= 6) ? nstm : stm;               \
        const int kk = ((TK) % 6) * 128;                                       \
        _Pragma("unroll") for (int q = 0; q < 4; ++q)                          \
            REG[q] = *reinterpret_cast<const float4*>(                         \
                &Ap[(size_t)(r0 + arow) * 768 + kk + acol + q * 4]);           \
    }

#define FT_WRITE(REG)                                                          \
    {                                                                          \
        int4 w0, w1;                                                           \
        w0.x = (int)pack2(REG[0].x, REG[0].y);                                 \
        w0.y = (int)pack2(REG[0].z, REG[0].w);                                 \
        w0.z = (int)pack2(REG[1].x, REG[1].y);                                 \
        w0.w = (int)pack2(REG[1].z, REG[1].w);                                 \
        w1.x = (int)pack2(REG[2].x, REG[2].y);                                 \
        w1.y = (int)pack2(REG[2].z, REG[2].w);                                 \
        w1.z = (int)pack2(REG[3].x, REG[3].y);                                 \
        w1.w = (int)pack2(REG[3].z, REG[3].w);                                 \
        *reinterpret_cast<int4*>(smA + adst0) = w0;                            \
        *reinterpret_cast<int4*>(smA + adst1) = w1;                            \
    }

// B fragments straight from global (L2-resident), row-major [N][KTOT]
#define LOADB(PTR, KTOT, K0)                                                   \
    _Pragma("unroll") for (int nt = 0; nt < 2; ++nt)                           \
        _Pragma("unroll") for (int ks = 0; ks < 4; ++ks) {                     \
            const int col = wc * 32 + nt * 16 + fr;                            \
            bf[nt][ks] = *reinterpret_cast<const bf16x8*>(                     \
                &PTR[(size_t)col * (KTOT) + (K0) + ks * 32 + h * 8]);          \
        }

#define GEMM_STEP(PHI)                                                         \
    _Pragma("unroll") for (int ks = 0; ks < 4; ++ks) {                         \
        bf16x8 a[2];                                                           \
        _Pragma("unroll") for (int mt = 0; mt < 2; ++mt) {                     \
            const uint32_t row = (uint32_t)(wr * 32 + mt * 16 + fr);           \
            a[mt] = *reinterpret_cast<const bf16x8*>(                          \
                (PHI) + row * 256u +                                           \
                (((uint32_t)(ks * 4 + h) ^ (row & 15u)) << 4));                \
        }                                                                      \
        _Pragma("unroll") for (int mt = 0; mt < 2; ++mt)                       \
            _Pragma("unroll") for (int nt = 0; nt < 2; ++nt)                   \
                acc[mt][nt] = __builtin_amdgcn_mfma_f32_16x16x32_bf16(         \
                    a[mt], bf[nt][ks], acc[mt][nt], 0, 0, 0);                  \
    }

#define DUMP_H(SO)                                                             \
    _Pragma("unroll") for (int nt = 0; nt < 2; ++nt) {                         \
        const int col = wc * 32 + nt * 16 + fr;                                \
        const float bv = bias[col];                                            \
        const int feat = (SO) + col;                                           \
        _Pragma("unroll") for (int mt = 0; mt < 2; ++mt) {                     \
            const int rowb = wr * 32 + mt * 16 + h * 4;                        \
            int2 o;                                                            \
            o.x = (int)pack2(acc[mt][nt][0] + bv, acc[mt][nt][1] + bv);        \
            o.y = (int)pack2(acc[mt][nt][2] + bv, acc[mt][nt][3] + bv);        \
            const uint32_t db = (uint32_t)feat * 128u +                        \
                ((uint32_t)((rowb >> 3) ^ (feat & 7)) << 4) +                  \
                (uint32_t)(rowb & 7) * 2u;                                     \
            *reinterpret_cast<int2*>(smHT + db) = o;                           \
            acc[mt][nt] = (f32x4){0.f, 0.f, 0.f, 0.f};                         \
        }                                                                      \
    }

#define EXPAND(DST, JF)                                                        \
    {                                                                          \
        const int feat = (JF) * 8 + w;                                         \
        const unsigned short xv = *reinterpret_cast<const unsigned short*>(    \
            smHT + (uint32_t)feat * 128u +                                     \
            ((uint32_t)((l >> 3) ^ (feat & 7)) << 4) + (uint32_t)(l & 7) * 2u);\
        const float x = bf2f(xv);                                              \
        float bs[8];                                                           \
        bspline8(x, bs);                                                       \
        const uint32_t pw0 = pack2(silu_f(x), bs[0]);                          \
        const uint32_t pw1 = pack2(bs[1], bs[2]);                              \
        const uint32_t pw2 = pack2(bs[3], bs[4]);                              \
        const uint32_t pw3 = pack2(bs[5], bs[6]);                              \
        const uint32_t pw4 = pack2(bs[7], 0.f);                                \
        const uint32_t d0 = (uint32_t)l * 256u +                               \
            ((uint32_t)((2 * w) ^ (l & 15)) << 4);                             \
        const uint32_t d1 = (uint32_t)l * 256u +                               \
            ((uint32_t)((2 * w + 1) ^ (l & 15)) << 4);                         \
        *reinterpret_cast<int4*>((DST) + d0) =                                 \
            make_int4((int)pw0, (int)pw1, (int)pw2, (int)pw3);                 \
        *reinterpret_cast<int4*>((DST) + d1) = make_int4((int)pw4, 0, 0, 0);   \
    }

#define BAR1()                                                                 \
    asm volatile("s_waitcnt lgkmcnt(0)" ::: "memory");                         \
    __builtin_amdgcn_sched_barrier(0);                                         \
    __builtin_amdgcn_s_barrier();
#define BAR2()                                                                 \
    __builtin_amdgcn_sched_barrier(0);                                         \
    __builtin_amdgcn_s_barrier();                                              \
    __builtin_amdgcn_sched_barrier(0);

    // ================= Phase 1: feature transform (both sides) =============
    FT_ISSUE(regY, 0);
    FT_ISSUE(regZ, 1);
#pragma unroll 1
    for (int pp = 0; pp < 6; ++pp) {
        // ---- even slot: tile 2pp (regY) ----
        FT_WRITE(regY);                        // compiler waits regY's loads
        if (pp < 5) FT_ISSUE(regY, 2 * pp + 2);
        LOADB(Wb, 768, ((2 * pp) % 6) * 128);
        BAR1();
        __builtin_amdgcn_s_setprio(1);
        GEMM_STEP(smA);
        __builtin_amdgcn_s_setprio(0);
        BAR2();
        // ---- odd slot: tile 2pp+1 (regZ) ----
        FT_WRITE(regZ);
        if (pp < 5) FT_ISSUE(regZ, 2 * pp + 3);
        LOADB(Wb, 768, ((2 * pp + 1) % 6) * 128);
        BAR1();
        __builtin_amdgcn_s_setprio(1);
        GEMM_STEP(smA);
        __builtin_amdgcn_s_setprio(0);
        if (pp == 2) { DUMP_H(0); }            // side 0 complete
        if (pp == 5) { DUMP_H(128); }          // side 1 complete
        asm volatile("s_waitcnt lgkmcnt(0)" ::: "memory");
        BAR2();
    }

    // ================= Phase 2: KAN1 GEMM (K = 256*16) =====================
    EXPAND(smA, 0);                            // prologue: phi0 for jb=0
#pragma unroll 1
    for (int jb = 0; jb < 32; ++jb) {
        char* phiC = (jb & 1) ? phi1 : smA;
        char* phiN = (jb & 1) ? smA : phi1;
        LOADB(Bp, 4096, jb * 128);             // issue early; hidden by barrier
        if (jb < 31) EXPAND(phiN, jb + 1);     // expand next while MFMA current
        BAR1();
        __builtin_amdgcn_s_setprio(1);
        GEMM_STEP(phiC);
        __builtin_amdgcn_s_setprio(0);
        BAR2();
    }

    // ================= Phase 3: KAN2 + sigmoid =============================
    unsigned short* smH2 = (unsigned short*)lds;   // phi region (32 KB free)
#pragma unroll
    for (int mt = 0; mt < 2; ++mt)
#pragma unroll
        for (int nt = 0; nt < 2; ++nt) {
            const int col = wc * 32 + nt * 16 + fr;
#pragma unroll
            for (int j = 0; j < 4; ++j) {
                const int row = wr * 32 + mt * 16 + h * 4 + j;
                smH2[row * 136 + col] = f2bf(acc[mt][nt][j]);
            }
        }
    __syncthreads();
    const int row2 = t >> 3, qd = t & 7;           // 8 threads/row, 16 cols each
    float sum = 0.f;
#pragma unroll 4
    for (int i = 0; i < 16; ++i) {
        const int j = qd * 16 + ((i + qd * 2) & 15);   // stagger banks
        const float x = bf2f(smH2[row2 * 136 + j]);
        float bs[8];
        bspline8(x, bs);
        const float4 s0 = *reinterpret_cast<const float4*>(&w2s[j * 8]);
        const float4 s1 = *reinterpret_cast<const float4*>(&w2s[j * 8 + 4]);
        float s = silu_f(x) * w2b[j];
        s += bs[0] * s0.x + bs[1] * s0.y + bs[2] * s0.z + bs[3] * s0.w;
        s += bs[4] * s1.x + bs[5] * s1.y + bs[6] * s1.z + bs[7] * s1.w;
        sum += s;
    }
    sum += __shfl_xor(sum, 1, 64);
    sum += __shfl_xor(sum, 2, 64);
    sum += __shfl_xor(sum, 4, 64);
    if (qd == 0) out[r0 + row2] = 1.0f / (1.0f + __expf(-sum));
}

// ---------------------------------------------------------------------------
extern "C" void kernel_launch(void* const* d_in, const int* in_sizes, int n_in,
                              void* d_out, int out_size, void* d_ws, size_t ws_size,
                              hipStream_t stream) {
    const float* stm  = (const float*)d_in[0];
    const float* nstm = (const float*)d_in[1];
    const float* ft_w = (const float*)d_in[2];
    const float* ft_b = (const float*)d_in[3];
    const float* k1bw = (const float*)d_in[4];
    const float* k1sw = (const float*)d_in[5];
    const float* k2bw = (const float*)d_in[6];
    const float* k2sw = (const float*)d_in[7];
    float* out = (float*)d_out;

    char* ws = (char*)d_ws;
    unsigned short* Wb = (unsigned short*)ws;                 //   196,608 B
    unsigned short* Bp = (unsigned short*)(ws + 196608);      // 1,048,576 B

    prep_ftw<<<384, 256, 0, stream>>>(ft_w, Wb);
    prep_bp<<<2048, 256, 0, stream>>>(k1bw, k1sw, Bp);
    kan_fused<<<512, 512, 0, stream>>>(stm, nstm, Wb, ft_b, Bp, k2bw, k2sw, out);
}

// Round 13
// 115.798 us; speedup vs baseline: 1.7306x; 1.7306x over previous
//
#include <hip/hip_runtime.h>
#include <hip/hip_bf16.h>
#include <math.h>
#include <stdint.h>

typedef __attribute__((ext_vector_type(8))) short bf16x8;
typedef __attribute__((ext_vector_type(4))) float f32x4;

__device__ __forceinline__ uint32_t pack2(float a, float b) {
    union { __hip_bfloat162 h2; uint32_t u; } c;
    c.h2 = __float22bfloat162_rn(make_float2(a, b));   // v_cvt_pk_bf16_f32
    return c.u;
}
__device__ __forceinline__ unsigned short f2bf(float f) {
    union { __hip_bfloat16 h; unsigned short u; } c;
    c.h = __float2bfloat16(f);
    return c.u;
}
__device__ __forceinline__ float bf2f(unsigned short h) {
    union { uint32_t u; float f; } c; c.u = ((uint32_t)h) << 16;
    return c.f;
}
__device__ __forceinline__ float silu_f(float x) {
    return x / (1.0f + __expf(-x));
}

// Uniform cardinal cubic B-spline bases on grid g_i = -2.2 + 0.4*i.
// Identical to the reference Cox-de-Boor recursion on this uniform grid.
__device__ __forceinline__ void bspline8(float x, float* __restrict__ b) {
    const float tt = (x + 2.2f) * 2.5f;
#pragma unroll
    for (int v = 0; v < 8; ++v) {
        float y = fabsf(tt - (float)(v + 2));
        float p = fmaxf(2.0f - y, 0.0f);
        float q = fmaxf(1.0f - y, 0.0f);
        b[v] = (p * p * p - 4.0f * q * q * q) * (1.0f / 6.0f);
    }
}

__device__ __forceinline__ void gload16(const void* g, void* l) {
    __builtin_amdgcn_global_load_lds(
        (const __attribute__((address_space(1))) void*)g,
        (__attribute__((address_space(3))) void*)l, 16, 0, 0);
}

// ---------------------------------------------------------------------------
// prep kernels
// ---------------------------------------------------------------------------
__global__ __launch_bounds__(256) void prep_ftw(const float* __restrict__ ftw,
                                                unsigned short* __restrict__ Wb) {
    const int idx = blockIdx.x * 256 + threadIdx.x;   // 98304 = 128*768
    Wb[idx] = f2bf(ftw[idx]);
}

__global__ __launch_bounds__(256) void prep_bp(const float* __restrict__ bw,
                                               const float* __restrict__ sw,
                                               unsigned short* __restrict__ Bp) {
    const int idx = blockIdx.x * 256 + threadIdx.x;   // 524288 = 128*4096
    const int n = idx >> 12;
    const int k = idx & 4095;
    const int f = k >> 4;
    const int v = k & 15;
    float val = 0.f;
    if (v == 0) val = bw[n * 256 + f];
    else if (v <= 8) val = sw[(size_t)(n * 256 + f) * 8 + (v - 1)];
    Bp[idx] = f2bf(val);
}

// ---------------------------------------------------------------------------
// FUSED, BM=128 rows/block, grid 256 (1 block/CU), block 512 (8 waves).
// Wave tile 64x64 everywhere: 8 ds_read_b128 feed 16 MFMA per k-chunk
// (2.5x better MFMA:LDS ratio than 32x32 -- the kernel was LDS-issue-bound).
//   Phase 1: BOTH sides concurrently: waves 0-3 = stm, 4-7 = nstm, sharing
//            one Wb tile/phase.  BK=64, 12 phases, depth-1 named-reg A
//            prefetch, Wb gload_lds (pre-swizzled src).  H^T -> LDS (64 KB).
//   Phase 2: KAN1 expanded-A GEMM, 32 steps: all 8 waves expand (2/thread),
//            waves 0-3 do 64x64-tile MFMA (64 MFMA, 32 reads each).
//   Phase 3: KAN2 reduce + sigmoid.
// LDS 128 KB: [0,64K) ph1{A0 16K|A1 16K|B 16K} / ph2{phi 32K|Bp 32K} / ph3 H2
//             [64K,128K) smHT [256 feat][128 rows] bf16, 16-chunk swizzled.
// ---------------------------------------------------------------------------
__global__ __launch_bounds__(512, 2) void kan_fused(
        const float* __restrict__ stm, const float* __restrict__ nstm,
        const unsigned short* __restrict__ Wb, const float* __restrict__ bias,
        const unsigned short* __restrict__ Bp,
        const float* __restrict__ w2b, const float* __restrict__ w2s,
        float* __restrict__ out) {
    __shared__ alignas(16) char lds[131072];
    char* smA0 = lds;                 // ph1: A side0 (16 KB)  | ph2: phi low
    char* smA1 = lds + 16384;         // ph1: A side1 (16 KB)  | ph2: phi high
    char* smB  = lds + 32768;         // ph1: Wb tile (16 KB)
    char* smB2 = lds + 32768;         // ph2: Bp tile (32 KB)
    char* phi  = lds;                 // ph2: phi [128 rows][128 k] (32 KB)
    char* smHT = lds + 65536;         // H^T [256 feat][128 rows] (64 KB)

    const int r0 = blockIdx.x * 128;
    const int t = threadIdx.x;
    const int l = t & 63, w = t >> 6;
    const int fr = l & 15, h = l >> 4;

    // ---- phase-1 wave mapping: side s, 2x2 over (rows 128, cols 128) ----
    const int s1 = w >> 2;            // side
    const int wrF = (w >> 1) & 1;     // row half (64)
    const int wcF = w & 1;            // col half (64)

    // ---- A staging: thread -> row t>>2, floats (t&3)*16 .. +15 ----
    const int arow = t >> 2;
    const int aq = t & 3;
    const uint32_t aw0 = (uint32_t)arow * 128u +
        ((uint32_t)((aq * 2) ^ (arow & 7)) << 4);
    const uint32_t aw1 = (uint32_t)arow * 128u +
        ((uint32_t)((aq * 2 + 1) ^ (arow & 7)) << 4);

    f32x4 acc[4][4];
#pragma unroll
    for (int mt = 0; mt < 4; ++mt)
#pragma unroll
        for (int nt = 0; nt < 4; ++nt) acc[mt][nt] = (f32x4){0.f, 0.f, 0.f, 0.f};

    float4 regY[8];                   // [0..3] side0, [4..7] side1

#define FT_ISSUE(TK)                                                           \
    {                                                                          \
        const size_t gb = (size_t)(r0 + arow) * 768 + (TK) * 64 + aq * 16;     \
        _Pragma("unroll") for (int q = 0; q < 4; ++q)                          \
            regY[q] = *reinterpret_cast<const float4*>(&stm[gb + q * 4]);      \
        _Pragma("unroll") for (int q = 0; q < 4; ++q)                          \
            regY[4 + q] = *reinterpret_cast<const float4*>(&nstm[gb + q * 4]); \
    }

#define FT_WRITE()                                                             \
    {                                                                          \
        int4 u0, u1;                                                           \
        u0.x = (int)pack2(regY[0].x, regY[0].y);                               \
        u0.y = (int)pack2(regY[0].z, regY[0].w);                               \
        u0.z = (int)pack2(regY[1].x, regY[1].y);                               \
        u0.w = (int)pack2(regY[1].z, regY[1].w);                               \
        u1.x = (int)pack2(regY[2].x, regY[2].y);                               \
        u1.y = (int)pack2(regY[2].z, regY[2].w);                               \
        u1.z = (int)pack2(regY[3].x, regY[3].y);                               \
        u1.w = (int)pack2(regY[3].z, regY[3].w);                               \
        *reinterpret_cast<int4*>(smA0 + aw0) = u0;                             \
        *reinterpret_cast<int4*>(smA0 + aw1) = u1;                             \
        u0.x = (int)pack2(regY[4].x, regY[4].y);                               \
        u0.y = (int)pack2(regY[4].z, regY[4].w);                               \
        u0.z = (int)pack2(regY[5].x, regY[5].y);                               \
        u0.w = (int)pack2(regY[5].z, regY[5].w);                               \
        u1.x = (int)pack2(regY[6].x, regY[6].y);                               \
        u1.y = (int)pack2(regY[6].z, regY[6].w);                               \
        u1.z = (int)pack2(regY[7].x, regY[7].y);                               \
        u1.w = (int)pack2(regY[7].z, regY[7].w);                               \
        *reinterpret_cast<int4*>(smA1 + aw0) = u0;                             \
        *reinterpret_cast<int4*>(smA1 + aw1) = u1;                             \
    }

    // ================= Phase 1 =============================================
    FT_ISSUE(0);
#pragma unroll 1
    for (int tk = 0; tk < 12; ++tk) {
        FT_WRITE();                               // waits prior A loads
        // Wb tile: 16 gload_lds (2/wave), cols 0..127 x 64 k
#pragma unroll
        for (int j = 0; j < 2; ++j) {
            const int i = w * 2 + j;
            const int col = i * 8 + (l >> 3);
            gload16(&Wb[(size_t)col * 768 + tk * 64 + (((l & 7) ^ (col & 7)) << 3)],
                    smB + i * 1024);
        }
        __builtin_amdgcn_sched_barrier(0);
        if (tk < 11) {
            FT_ISSUE(tk + 1);
            asm volatile("s_waitcnt vmcnt(8)" ::: "memory");  // B done, A flying
        } else {
            asm volatile("s_waitcnt vmcnt(0)" ::: "memory");
        }
        asm volatile("s_waitcnt lgkmcnt(0)" ::: "memory");
        __builtin_amdgcn_sched_barrier(0);
        __builtin_amdgcn_s_barrier();
        // compute: 2 k-chunks of 32
        const char* As = s1 ? smA1 : smA0;
        __builtin_amdgcn_s_setprio(1);
#pragma unroll
        for (int ks = 0; ks < 2; ++ks) {
            bf16x8 a[4], b[4];
#pragma unroll
            for (int mt = 0; mt < 4; ++mt) {
                const uint32_t row = (uint32_t)(wrF * 64 + mt * 16 + fr);
                a[mt] = *reinterpret_cast<const bf16x8*>(
                    As + row * 128u + (((uint32_t)(ks * 4 + h) ^ (row & 7u)) << 4));
            }
#pragma unroll
            for (int nt = 0; nt < 4; ++nt) {
                const uint32_t col = (uint32_t)(wcF * 64 + nt * 16 + fr);
                b[nt] = *reinterpret_cast<const bf16x8*>(
                    smB + col * 128u + (((uint32_t)(ks * 4 + h) ^ (col & 7u)) << 4));
            }
#pragma unroll
            for (int mt = 0; mt < 4; ++mt)
#pragma unroll
                for (int nt = 0; nt < 4; ++nt)
                    acc[mt][nt] = __builtin_amdgcn_mfma_f32_16x16x32_bf16(
                        a[mt], b[nt], acc[mt][nt], 0, 0, 0);
        }
        __builtin_amdgcn_s_setprio(0);
        asm volatile("s_waitcnt lgkmcnt(0)" ::: "memory");
        __builtin_amdgcn_sched_barrier(0);
        __builtin_amdgcn_s_barrier();
    }
    // dump H^T (bias add, cvt) -> smHT, rezero acc
#pragma unroll
    for (int nt = 0; nt < 4; ++nt) {
        const int col = wcF * 64 + nt * 16 + fr;
        const float bv = bias[col];
        const int feat = s1 * 128 + col;
#pragma unroll
        for (int mt = 0; mt < 4; ++mt) {
            const int rowb = wrF * 64 + mt * 16 + h * 4;
            int2 o;
            o.x = (int)pack2(acc[mt][nt][0] + bv, acc[mt][nt][1] + bv);
            o.y = (int)pack2(acc[mt][nt][2] + bv, acc[mt][nt][3] + bv);
            const uint32_t db = (uint32_t)feat * 256u +
                ((uint32_t)((rowb >> 3) ^ (feat & 15)) << 4) +
                (uint32_t)(rowb & 7) * 2u;
            *reinterpret_cast<int2*>(smHT + db) = o;
            acc[mt][nt] = (f32x4){0.f, 0.f, 0.f, 0.f};
        }
    }
    asm volatile("s_waitcnt lgkmcnt(0)" ::: "memory");
    __builtin_amdgcn_sched_barrier(0);
    __builtin_amdgcn_s_barrier();

    // ================= Phase 2: KAN1 GEMM (K = 256*16) =====================
    const int erow = t & 127;         // expansion row
    const int ef = t >> 7;            // 0..3 -> features ef, ef+4
    const int wr2 = (w >> 1) & 1;     // gemm waves 0-3: 2x2 of 64x64
    const int wc2 = w & 1;

#pragma unroll 1
    for (int jb = 0; jb < 32; ++jb) {
        // 1. Bp tile: 32 gload_lds (4/wave), [128 cols][128 k]
#pragma unroll
        for (int j = 0; j < 4; ++j) {
            const int i = w * 4 + j;
            const int col = i * 4 + (l >> 4);
            gload16(&Bp[(size_t)col * 4096 + jb * 128 +
                        (((l & 15) ^ (col & 15)) << 3)],
                    smB2 + i * 1024);
        }
        __builtin_amdgcn_sched_barrier(0);
        // 2. expansion: 2 features per thread (all 8 waves)
#pragma unroll
        for (int e = 0; e < 2; ++e) {
            const int f = ef + e * 4;
            const int feat = jb * 8 + f;
            const unsigned short xv = *reinterpret_cast<const unsigned short*>(
                smHT + (uint32_t)feat * 256u +
                ((uint32_t)((erow >> 3) ^ (feat & 15)) << 4) +
                (uint32_t)(erow & 7) * 2u);
            const float x = bf2f(xv);
            float bs[8];
            bspline8(x, bs);
            const uint32_t p0 = pack2(silu_f(x), bs[0]);
            const uint32_t p1 = pack2(bs[1], bs[2]);
            const uint32_t p2 = pack2(bs[3], bs[4]);
            const uint32_t p3 = pack2(bs[5], bs[6]);
            const uint32_t p4 = pack2(bs[7], 0.f);
            const uint32_t d0 = (uint32_t)erow * 256u +
                ((uint32_t)((2 * f) ^ (erow & 15)) << 4);
            const uint32_t d1 = (uint32_t)erow * 256u +
                ((uint32_t)((2 * f + 1) ^ (erow & 15)) << 4);
            *reinterpret_cast<int4*>(phi + d0) =
                make_int4((int)p0, (int)p1, (int)p2, (int)p3);
            *reinterpret_cast<int4*>(phi + d1) = make_int4((int)p4, 0, 0, 0);
        }
        asm volatile("s_waitcnt vmcnt(0) lgkmcnt(0)" ::: "memory");
        __builtin_amdgcn_sched_barrier(0);
        __builtin_amdgcn_s_barrier();
        // 3. GEMM: waves 0-3, 64x64 tile, 4 k-chunks
        if (w < 4) {
            __builtin_amdgcn_s_setprio(1);
#pragma unroll
            for (int ks = 0; ks < 4; ++ks) {
                bf16x8 a[4], b[4];
#pragma unroll
                for (int mt = 0; mt < 4; ++mt) {
                    const uint32_t row = (uint32_t)(wr2 * 64 + mt * 16 + fr);
                    a[mt] = *reinterpret_cast<const bf16x8*>(
                        phi + row * 256u +
                        (((uint32_t)(ks * 4 + h) ^ (row & 15u)) << 4));
                }
#pragma unroll
                for (int nt = 0; nt < 4; ++nt) {
                    const uint32_t col = (uint32_t)(wc2 * 64 + nt * 16 + fr);
                    b[nt] = *reinterpret_cast<const bf16x8*>(
                        smB2 + col * 256u +
                        (((uint32_t)(ks * 4 + h) ^ (col & 15u)) << 4));
                }
#pragma unroll
                for (int mt = 0; mt < 4; ++mt)
#pragma unroll
                    for (int nt = 0; nt < 4; ++nt)
                        acc[mt][nt] = __builtin_amdgcn_mfma_f32_16x16x32_bf16(
                            a[mt], b[nt], acc[mt][nt], 0, 0, 0);
            }
            __builtin_amdgcn_s_setprio(0);
        }
        asm volatile("s_waitcnt lgkmcnt(0)" ::: "memory");
        __builtin_amdgcn_sched_barrier(0);
        __builtin_amdgcn_s_barrier();
    }

    // ================= Phase 3: KAN2 + sigmoid =============================
    unsigned short* smH2 = (unsigned short*)lds;   // [128][136] bf16 (34.8 KB)
    if (w < 4) {
#pragma unroll
        for (int mt = 0; mt < 4; ++mt)
#pragma unroll
            for (int nt = 0; nt < 4; ++nt) {
                const int col = wc2 * 64 + nt * 16 + fr;
#pragma unroll
                for (int j = 0; j < 4; ++j) {
                    const int row = wr2 * 64 + mt * 16 + h * 4 + j;
                    smH2[row * 136 + col] = f2bf(acc[mt][nt][j]);
                }
            }
    }
    __syncthreads();
    const int row2 = t >> 2, qd = t & 3;           // 4 threads/row, 32 cols
    float sum = 0.f;
#pragma unroll 4
    for (int i = 0; i < 32; ++i) {
        const int j = qd * 32 + ((i + qd * 8) & 31);   // stagger banks
        const float x = bf2f(smH2[row2 * 136 + j]);
        float bs[8];
        bspline8(x, bs);
        const float4 s0 = *reinterpret_cast<const float4*>(&w2s[j * 8]);
        const float4 s1 = *reinterpret_cast<const float4*>(&w2s[j * 8 + 4]);
        float s = silu_f(x) * w2b[j];
        s += bs[0] * s0.x + bs[1] * s0.y + bs[2] * s0.z + bs[3] * s0.w;
        s += bs[4] * s1.x + bs[5] * s1.y + bs[6] * s1.z + bs[7] * s1.w;
        sum += s;
    }
    sum += __shfl_xor(sum, 1, 64);
    sum += __shfl_xor(sum, 2, 64);
    if (qd == 0) out[r0 + row2] = 1.0f / (1.0f + __expf(-sum));
}

// ---------------------------------------------------------------------------
extern "C" void kernel_launch(void* const* d_in, const int* in_sizes, int n_in,
                              void* d_out, int out_size, void* d_ws, size_t ws_size,
                              hipStream_t stream) {
    const float* stm  = (const float*)d_in[0];
    const float* nstm = (const float*)d_in[1];
    const float* ft_w = (const float*)d_in[2];
    const float* ft_b = (const float*)d_in[3];
    const float* k1bw = (const float*)d_in[4];
    const float* k1sw = (const float*)d_in[5];
    const float* k2bw = (const float*)d_in[6];
    const float* k2sw = (const float*)d_in[7];
    float* out = (float*)d_out;

    char* ws = (char*)d_ws;
    unsigned short* Wb = (unsigned short*)ws;                 //   196,608 B
    unsigned short* Bp = (unsigned short*)(ws + 196608);      // 1,048,576 B

    prep_ftw<<<384, 256, 0, stream>>>(ft_w, Wb);
    prep_bp<<<2048, 256, 0, stream>>>(k1bw, k1sw, Bp);
    kan_fused<<<256, 512, 0, stream>>>(stm, nstm, Wb, ft_b, Bp, k2bw, k2sw, out);
}

// Round 14
// 110.375 us; speedup vs baseline: 1.8157x; 1.0491x over previous
//
#include <hip/hip_runtime.h>
#include <hip/hip_bf16.h>
#include <math.h>
#include <stdint.h>

typedef __attribute__((ext_vector_type(8))) short bf16x8;
typedef __attribute__((ext_vector_type(4))) float f32x4;

__device__ __forceinline__ uint32_t pack2(float a, float b) {
    union { __hip_bfloat162 h2; uint32_t u; } c;
    c.h2 = __float22bfloat162_rn(make_float2(a, b));   // v_cvt_pk_bf16_f32
    return c.u;
}
__device__ __forceinline__ unsigned short f2bf(float f) {
    union { __hip_bfloat16 h; unsigned short u; } c;
    c.h = __float2bfloat16(f);
    return c.u;
}
__device__ __forceinline__ float bf2f(unsigned short h) {
    union { uint32_t u; float f; } c; c.u = ((uint32_t)h) << 16;
    return c.f;
}
__device__ __forceinline__ float silu_f(float x) {
    return x / (1.0f + __expf(-x));
}

// Uniform cardinal cubic B-spline bases on grid g_i = -2.2 + 0.4*i.
// Identical to the reference Cox-de-Boor recursion on this uniform grid.
__device__ __forceinline__ void bspline8(float x, float* __restrict__ b) {
    const float tt = (x + 2.2f) * 2.5f;
#pragma unroll
    for (int v = 0; v < 8; ++v) {
        float y = fabsf(tt - (float)(v + 2));
        float p = fmaxf(2.0f - y, 0.0f);
        float q = fmaxf(1.0f - y, 0.0f);
        b[v] = (p * p * p - 4.0f * q * q * q) * (1.0f / 6.0f);
    }
}

// ---------------------------------------------------------------------------
// prep kernels: weights -> WAVE-FRAGMENT-CONTIGUOUS bf16 layout
//   [tile][wc(4)][nt(2)][ks(4)][lane(64)][8 elems]
// so a wave's MFMA B-fragment load is one fully-coalesced 1 KB instruction.
//   col = wc*32 + nt*16 + (l&15);  k = tile*128 + ks*32 + (l>>4)*8 + e
// ---------------------------------------------------------------------------
__global__ __launch_bounds__(256) void prep_wbf(const float* __restrict__ ftw,
                                                unsigned short* __restrict__ WbF) {
    const int idx = blockIdx.x * 256 + threadIdx.x;   // 98304 = 6*16384
    const int e = idx & 7, l = (idx >> 3) & 63, ks = (idx >> 9) & 3;
    const int nt = (idx >> 11) & 1, wc = (idx >> 12) & 3, tile = idx >> 14;
    const int col = wc * 32 + nt * 16 + (l & 15);
    const int k = tile * 128 + ks * 32 + (l >> 4) * 8 + e;
    WbF[idx] = f2bf(ftw[(size_t)col * 768 + k]);
}

__global__ __launch_bounds__(256) void prep_bpf(const float* __restrict__ bw,
                                                const float* __restrict__ sw,
                                                unsigned short* __restrict__ BpF) {
    const int idx = blockIdx.x * 256 + threadIdx.x;   // 524288 = 32*16384
    const int e = idx & 7, l = (idx >> 3) & 63, ks = (idx >> 9) & 3;
    const int nt = (idx >> 11) & 1, wc = (idx >> 12) & 3, jb = idx >> 14;
    const int col = wc * 32 + nt * 16 + (l & 15);
    const int k = jb * 128 + ks * 32 + (l >> 4) * 8 + e;
    const int f = k >> 4, v = k & 15;
    float val = 0.f;
    if (v == 0) val = bw[col * 256 + f];
    else if (v <= 8) val = sw[(size_t)(col * 256 + f) * 8 + (v - 1)];
    BpF[idx] = f2bf(val);
}

// ---------------------------------------------------------------------------
// FUSED, BM=64, 2 blocks/CU (LDS 64 KB), grid 512, block 512 (8 waves 2x4,
// wave tile 32r x 32c).  B NEVER touches LDS: fragment-contiguous WbF/BpF
// loads go straight global->VGPR (1 KB coalesced per instr, L2-resident),
// consumed with compiler-counted vmcnt -- NO vmcnt(0) drains anywhere.
//   Phase 1: FT GEMM both sides (12 BK=128 tiles), depth-2 named-reg A
//            prefetch -> cvt -> swizzled smA.  H^T -> smHT (LDS only).
//   Phase 2: KAN1 expanded-A GEMM, 32 steps, phi DOUBLE-buffered
//            (expand next while MFMA current); only lgkm waits at barriers.
//   Phase 3: KAN2 reduce + sigmoid.
// ---------------------------------------------------------------------------
__global__ __launch_bounds__(512, 4) void kan_fused(
        const float* __restrict__ stm, const float* __restrict__ nstm,
        const unsigned short* __restrict__ WbF, const float* __restrict__ bias,
        const unsigned short* __restrict__ BpF,
        const float* __restrict__ w2b, const float* __restrict__ w2s,
        float* __restrict__ out) {
    __shared__ alignas(16) char lds[65536];
    char* smA  = lds;            // 16 KB: ph1 A tile / ph2 phi0 / ph3 smH2
    char* phi1 = lds + 16384;    // 16 KB: ph2 phi1
    char* smHT = lds + 32768;    // 32 KB: H^T [256 feat][64 rows], swizzled

    const int r0 = blockIdx.x * 64;
    const int t = threadIdx.x;
    const int l = t & 63, w = t >> 6;
    const int fr = l & 15, h = l >> 4;
    const int wr = w >> 2, wc = w & 3;        // 2x4 wave grid, tile 32r x 32c

    // A staging geometry: thread -> row (t>>3), 16 floats at col (t&7)*16
    const int arow = t >> 3;
    const int acol = (t & 7) * 16;
    const uint32_t adst0 = (uint32_t)arow * 256u +
        ((uint32_t)(((t & 7) * 2) ^ (arow & 15)) << 4);
    const uint32_t adst1 = (uint32_t)arow * 256u +
        ((uint32_t)(((t & 7) * 2 + 1) ^ (arow & 15)) << 4);

    f32x4 acc[2][2];
#pragma unroll
    for (int mt = 0; mt < 2; ++mt)
#pragma unroll
        for (int nt = 0; nt < 2; ++nt) acc[mt][nt] = (f32x4){0.f, 0.f, 0.f, 0.f};

    float4 regY[4], regZ[4];
    bf16x8 bf[2][4];   // B fragments (fully-unrolled static indexing)

#define FT_ISSUE(REG, TK)                                                      \
    {                                                                          \
        const float* __restrict__ Ap = ((TK) >= 6) ? nstm : stm;               \
        const int kk = ((TK) % 6) * 128;                                       \
        _Pragma("unroll") for (int q = 0; q < 4; ++q)                          \
            REG[q] = *reinterpret_cast<const float4*>(                         \
                &Ap[(size_t)(r0 + arow) * 768 + kk + acol + q * 4]);           \
    }

#define FT_WRITE(REG)                                                          \
    {                                                                          \
        int4 w0, w1;                                                           \
        w0.x = (int)pack2(REG[0].x, REG[0].y);                                 \
        w0.y = (int)pack2(REG[0].z, REG[0].w);                                 \
        w0.z = (int)pack2(REG[1].x, REG[1].y);                                 \
        w0.w = (int)pack2(REG[1].z, REG[1].w);                                 \
        w1.x = (int)pack2(REG[2].x, REG[2].y);                                 \
        w1.y = (int)pack2(REG[2].z, REG[2].w);                                 \
        w1.z = (int)pack2(REG[3].x, REG[3].y);                                 \
        w1.w = (int)pack2(REG[3].z, REG[3].w);                                 \
        *reinterpret_cast<int4*>(smA + adst0) = w0;                            \
        *reinterpret_cast<int4*>(smA + adst1) = w1;                            \
    }

// B fragments from fragment-contiguous layout: one 1 KB coalesced load each
#define LOADF(PTR, TILE)                                                       \
    {                                                                          \
        const unsigned short* __restrict__ fb =                                \
            (PTR) + (size_t)(TILE) * 16384 + wc * 4096 + l * 8;                \
        _Pragma("unroll") for (int nt = 0; nt < 2; ++nt)                       \
            _Pragma("unroll") for (int ks = 0; ks < 4; ++ks)                   \
                bf[nt][ks] = *reinterpret_cast<const bf16x8*>(                 \
                    fb + nt * 2048 + ks * 512);                                \
    }

#define GEMM_STEP(PHI)                                                         \
    _Pragma("unroll") for (int ks = 0; ks < 4; ++ks) {                         \
        bf16x8 a[2];                                                           \
        _Pragma("unroll") for (int mt = 0; mt < 2; ++mt) {                     \
            const uint32_t row = (uint32_t)(wr * 32 + mt * 16 + fr);           \
            a[mt] = *reinterpret_cast<const bf16x8*>(                          \
                (PHI) + row * 256u +                                           \
                (((uint32_t)(ks * 4 + h) ^ (row & 15u)) << 4));                \
        }                                                                      \
        _Pragma("unroll") for (int mt = 0; mt < 2; ++mt)                       \
            _Pragma("unroll") for (int nt = 0; nt < 2; ++nt)                   \
                acc[mt][nt] = __builtin_amdgcn_mfma_f32_16x16x32_bf16(         \
                    a[mt], bf[nt][ks], acc[mt][nt], 0, 0, 0);                  \
    }

#define DUMP_H(SO)                                                             \
    _Pragma("unroll") for (int nt = 0; nt < 2; ++nt) {                         \
        const int col = wc * 32 + nt * 16 + fr;                                \
        const float bv = bias[col];                                            \
        const int feat = (SO) + col;                                           \
        _Pragma("unroll") for (int mt = 0; mt < 2; ++mt) {                     \
            const int rowb = wr * 32 + mt * 16 + h * 4;                        \
            int2 o;                                                            \
            o.x = (int)pack2(acc[mt][nt][0] + bv, acc[mt][nt][1] + bv);        \
            o.y = (int)pack2(acc[mt][nt][2] + bv, acc[mt][nt][3] + bv);        \
            const uint32_t db = (uint32_t)feat * 128u +                        \
                ((uint32_t)((rowb >> 3) ^ (feat & 7)) << 4) +                  \
                (uint32_t)(rowb & 7) * 2u;                                     \
            *reinterpret_cast<int2*>(smHT + db) = o;                           \
            acc[mt][nt] = (f32x4){0.f, 0.f, 0.f, 0.f};                         \
        }                                                                      \
    }

#define EXPAND(DST, JF)                                                        \
    {                                                                          \
        const int feat = (JF) * 8 + w;                                         \
        const unsigned short xv = *reinterpret_cast<const unsigned short*>(    \
            smHT + (uint32_t)feat * 128u +                                     \
            ((uint32_t)((l >> 3) ^ (feat & 7)) << 4) + (uint32_t)(l & 7) * 2u);\
        const float x = bf2f(xv);                                              \
        float bs[8];                                                           \
        bspline8(x, bs);                                                       \
        const uint32_t pw0 = pack2(silu_f(x), bs[0]);                          \
        const uint32_t pw1 = pack2(bs[1], bs[2]);                              \
        const uint32_t pw2 = pack2(bs[3], bs[4]);                              \
        const uint32_t pw3 = pack2(bs[5], bs[6]);                              \
        const uint32_t pw4 = pack2(bs[7], 0.f);                                \
        const uint32_t d0 = (uint32_t)l * 256u +                               \
            ((uint32_t)((2 * w) ^ (l & 15)) << 4);                             \
        const uint32_t d1 = (uint32_t)l * 256u +                               \
            ((uint32_t)((2 * w + 1) ^ (l & 15)) << 4);                         \
        *reinterpret_cast<int4*>((DST) + d0) =                                 \
            make_int4((int)pw0, (int)pw1, (int)pw2, (int)pw3);                 \
        *reinterpret_cast<int4*>((DST) + d1) = make_int4((int)pw4, 0, 0, 0);   \
    }

#define BAR1()                                                                 \
    asm volatile("s_waitcnt lgkmcnt(0)" ::: "memory");                         \
    __builtin_amdgcn_sched_barrier(0);                                         \
    __builtin_amdgcn_s_barrier();
#define BAR2()                                                                 \
    __builtin_amdgcn_sched_barrier(0);                                         \
    __builtin_amdgcn_s_barrier();                                              \
    __builtin_amdgcn_sched_barrier(0);

    // ================= Phase 1: feature transform (both sides) =============
    FT_ISSUE(regY, 0);
    FT_ISSUE(regZ, 1);
#pragma unroll 1
    for (int pp = 0; pp < 6; ++pp) {
        // ---- even slot: tile 2pp (regY) ----
        FT_WRITE(regY);                        // compiler waits regY's loads
        if (pp < 5) FT_ISSUE(regY, 2 * pp + 2);
        LOADF(WbF, (2 * pp) % 6);
        BAR1();
        __builtin_amdgcn_s_setprio(1);
        GEMM_STEP(smA);
        __builtin_amdgcn_s_setprio(0);
        BAR2();
        // ---- odd slot: tile 2pp+1 (regZ) ----
        FT_WRITE(regZ);
        if (pp < 5) FT_ISSUE(regZ, 2 * pp + 3);
        LOADF(WbF, (2 * pp + 1) % 6);
        BAR1();
        __builtin_amdgcn_s_setprio(1);
        GEMM_STEP(smA);
        __builtin_amdgcn_s_setprio(0);
        if (pp == 2) { DUMP_H(0); }            // side 0 complete
        if (pp == 5) { DUMP_H(128); }          // side 1 complete
        asm volatile("s_waitcnt lgkmcnt(0)" ::: "memory");
        BAR2();
    }

    // ================= Phase 2: KAN1 GEMM (K = 256*16) =====================
    EXPAND(smA, 0);                            // prologue: phi0 for jb=0
#pragma unroll 1
    for (int jb = 0; jb < 32; ++jb) {
        char* phiC = (jb & 1) ? phi1 : smA;
        char* phiN = (jb & 1) ? smA : phi1;
        LOADF(BpF, jb);                        // 8x 1KB coalesced reg loads
        if (jb < 31) EXPAND(phiN, jb + 1);     // expand next while MFMA current
        BAR1();
        __builtin_amdgcn_s_setprio(1);
        GEMM_STEP(phiC);
        __builtin_amdgcn_s_setprio(0);
        BAR2();
    }

    // ================= Phase 3: KAN2 + sigmoid =============================
    unsigned short* smH2 = (unsigned short*)lds;   // phi region (32 KB free)
#pragma unroll
    for (int mt = 0; mt < 2; ++mt)
#pragma unroll
        for (int nt = 0; nt < 2; ++nt) {
            const int col = wc * 32 + nt * 16 + fr;
#pragma unroll
            for (int j = 0; j < 4; ++j) {
                const int row = wr * 32 + mt * 16 + h * 4 + j;
                smH2[row * 136 + col] = f2bf(acc[mt][nt][j]);
            }
        }
    __syncthreads();
    const int row2 = t >> 3, qd = t & 7;           // 8 threads/row, 16 cols each
    float sum = 0.f;
#pragma unroll 4
    for (int i = 0; i < 16; ++i) {
        const int j = qd * 16 + ((i + qd * 2) & 15);   // stagger banks
        const float x = bf2f(smH2[row2 * 136 + j]);
        float bs[8];
        bspline8(x, bs);
        const float4 s0 = *reinterpret_cast<const float4*>(&w2s[j * 8]);
        const float4 s1 = *reinterpret_cast<const float4*>(&w2s[j * 8 + 4]);
        float s = silu_f(x) * w2b[j];
        s += bs[0] * s0.x + bs[1] * s0.y + bs[2] * s0.z + bs[3] * s0.w;
        s += bs[4] * s1.x + bs[5] * s1.y + bs[6] * s1.z + bs[7] * s1.w;
        sum += s;
    }
    sum += __shfl_xor(sum, 1, 64);
    sum += __shfl_xor(sum, 2, 64);
    sum += __shfl_xor(sum, 4, 64);
    if (qd == 0) out[r0 + row2] = 1.0f / (1.0f + __expf(-sum));
}

// ---------------------------------------------------------------------------
extern "C" void kernel_launch(void* const* d_in, const int* in_sizes, int n_in,
                              void* d_out, int out_size, void* d_ws, size_t ws_size,
                              hipStream_t stream) {
    const float* stm  = (const float*)d_in[0];
    const float* nstm = (const float*)d_in[1];
    const float* ft_w = (const float*)d_in[2];
    const float* ft_b = (const float*)d_in[3];
    const float* k1bw = (const float*)d_in[4];
    const float* k1sw = (const float*)d_in[5];
    const float* k2bw = (const float*)d_in[6];
    const float* k2sw = (const float*)d_in[7];
    float* out = (float*)d_out;

    char* ws = (char*)d_ws;
    unsigned short* WbF = (unsigned short*)ws;                //   196,608 B
    unsigned short* BpF = (unsigned short*)(ws + 196608);     // 1,048,576 B

    prep_wbf<<<384, 256, 0, stream>>>(ft_w, WbF);
    prep_bpf<<<2048, 256, 0, stream>>>(k1bw, k1sw, BpF);
    kan_fused<<<512, 512, 0, stream>>>(stm, nstm, WbF, ft_b, BpF, k2bw, k2sw, out);
}